// Round 14
// baseline (972.571 us; speedup 1.0000x reference)
//
#include <hip/hip_runtime.h>

#define NN 100000
#define NE 1600000
#define FD 64
#define KK 3
#define NF (NN*FD)            // 6,400,000
#define EPSBN 1e-5f
#define SBLK ((NN + 255) / 256)   // 391
#define BLK64 ((NN + 63) / 64)    // 1563
#define DEGSCALE 262144.0f        // 2^18 fixed-point for weighted degree

typedef unsigned short ushort;
typedef unsigned int uint;
typedef __attribute__((ext_vector_type(8))) short short8;
typedef __attribute__((ext_vector_type(4))) float f32x4;

#define MFMA __builtin_amdgcn_mfma_f32_16x16x32_bf16

__device__ inline float bf2f(ushort u) { return __uint_as_float((unsigned)u << 16); }
__device__ inline ushort f2bf(float v) {
  unsigned u = __float_as_uint(v); u += 0x7FFF + ((u >> 16) & 1);
  return (ushort)(u >> 16);
}
// split a,b into packed hi-word and lo-word (hi = rnd(v), lo = rnd(v - hi))
__device__ inline void split2(float a, float b, uint& hi, uint& lo) {
  ushort ha = f2bf(a), hb = f2bf(b);
  float ra = a - bf2f(ha), rb = b - bf2f(hb);
  hi = (uint)ha | ((uint)hb << 16);
  lo = (uint)f2bf(ra) | ((uint)f2bf(rb) << 16);
}

// ---------------- graph norm + CSR build ----------------
__global__ void k_degcnt(const int* __restrict__ col, const float* __restrict__ w,
                         unsigned long long* __restrict__ dc) {
  int e = blockIdx.x * 256 + threadIdx.x;
  if (e < NE) {
    unsigned fx = __float2uint_rn(w[e] * DEGSCALE);
    atomicAdd(&dc[col[e]], (1ULL << 32) | (unsigned long long)fx);
  }
}

__global__ __launch_bounds__(256) void k_sblk(const unsigned long long* __restrict__ dc,
                                              float* __restrict__ dis, int* __restrict__ cnt,
                                              int* __restrict__ part) {
  int i = blockIdx.x * 256 + threadIdx.x;
  int v = 0;
  if (i < NN) {
    unsigned long long u = dc[i];
    float d = (float)(unsigned)u * (1.0f / DEGSCALE);
    dis[i] = d > 0.f ? rsqrtf(d) : 0.f;
    v = (int)(u >> 32);
    cnt[i] = v;
  }
#pragma unroll
  for (int off = 32; off; off >>= 1) v += __shfl_down(v, off);
  __shared__ int ws[4];
  if ((threadIdx.x & 63) == 0) ws[threadIdx.x >> 6] = v;
  __syncthreads();
  if (threadIdx.x == 0) part[blockIdx.x] = ws[0] + ws[1] + ws[2] + ws[3];
}

__global__ __launch_bounds__(512) void k_sscan(const int* __restrict__ part,
                                               int* __restrict__ base) {
  __shared__ int ls[512];
  int tid = threadIdx.x;
  int v = (tid < SBLK) ? part[tid] : 0;
  ls[tid] = v;
  __syncthreads();
  for (int off = 1; off < 512; off <<= 1) {
    int u = (tid >= off) ? ls[tid - off] : 0;
    __syncthreads();
    ls[tid] += u;
    __syncthreads();
  }
  base[tid] = tid ? ls[tid - 1] : 0;
}

__global__ __launch_bounds__(256) void k_sfin(const int* __restrict__ cnt,
                                              const int* __restrict__ base,
                                              int* __restrict__ rowstart,
                                              int* __restrict__ cursor) {
  __shared__ int ls[256];
  int i = blockIdx.x * 256 + threadIdx.x;
  int v = (i < NN) ? cnt[i] : 0;
  ls[threadIdx.x] = v;
  __syncthreads();
  for (int off = 1; off < 256; off <<= 1) {
    int u = (threadIdx.x >= off) ? ls[threadIdx.x - off] : 0;
    __syncthreads();
    ls[threadIdx.x] += u;
    __syncthreads();
  }
  int excl = base[blockIdx.x] + ls[threadIdx.x] - v;
  if (i < NN) {
    rowstart[i] = excl;
    cursor[i] = excl;
    if (i == NN - 1) rowstart[NN] = excl + v;
  }
}

__global__ void k_place(const int* __restrict__ row, const int* __restrict__ col,
                        const float* __restrict__ w, const float* __restrict__ dis,
                        int* __restrict__ cursor, int2* __restrict__ edges) {
  int e = blockIdx.x * 256 + threadIdx.x;
  if (e >= NE) return;
  int r = row[e], c = col[e];
  float nm = dis[r] * w[e] * dis[c];
  int p = atomicAdd(&cursor[c], 1);
  edges[p] = make_int2(r, __float_as_int(nm));
}

// ---------------- weight fragment prep (per layer, hi + lo) ----------------
// hi frag[(which*3+k)*8 + ct*2 + ks][lane]; lo at +6144 uint4.
// which: 0 = iw[k], 1 = w[k][0], 2 = rw[k][0], 3 = rw[k][1]
__global__ __launch_bounds__(64) void k_wfrag(const float* __restrict__ iw,
                                              const float* __restrict__ w,
                                              const float* __restrict__ rw,
                                              uint4* __restrict__ frag) {
  int m = blockIdx.x;
  int which = m / 3, k = m % 3;
  const float* src;
  if (which == 0) src = iw + k * 4096;
  else if (which == 1) src = w + k * 4096;
  else if (which == 2) src = rw + k * 8192;
  else src = rw + k * 8192 + 4096;
  int sub = blockIdx.y;            // ct*2 + ks
  int ks = sub & 1, ct = sub >> 1;
  int l = threadIdx.x;
  int r0 = ks * 32 + (l >> 4) * 8;
  int c = ct * 16 + (l & 15);
  uint4 oh, ol;
  split2(src[(r0 + 0) * 64 + c], src[(r0 + 1) * 64 + c], oh.x, ol.x);
  split2(src[(r0 + 2) * 64 + c], src[(r0 + 3) * 64 + c], oh.y, ol.y);
  split2(src[(r0 + 4) * 64 + c], src[(r0 + 5) * 64 + c], oh.z, ol.z);
  split2(src[(r0 + 6) * 64 + c], src[(r0 + 7) * 64 + c], oh.w, ol.w);
  frag[(m * 8 + sub) * 64 + l] = oh;
  frag[6144 + (m * 8 + sub) * 64 + l] = ol;
}

// ---------------- f32 -> bf16 hi/lo planes ----------------
__global__ void k_tobf2(const float* __restrict__ in,
                        ushort* __restrict__ hi, ushort* __restrict__ lo) {
  long i = ((long)blockIdx.x * 256 + threadIdx.x) * 4;
  float4 v = *(const float4*)(in + i);
  uint2 uh, ul;
  split2(v.x, v.y, uh.x, ul.x);
  split2(v.z, v.w, uh.y, ul.y);
  *(uint2*)(hi + i) = uh;
  *(uint2*)(lo + i) = ul;
}

#define RED2(v) do { (v) += __shfl_xor((v), 16); (v) += __shfl_xor((v), 32); } while (0)

#define G0STEP(EV) do { \
  int2 _e = (EV); \
  float _m = __int_as_float(_e.y); \
  uint2 _u = ((const uint2*)(xhi + (long)_e.x * 64))[fi]; \
  a0 = fmaf(bf2f((ushort)_u.x), _m, a0); a1 = fmaf(bf2f((ushort)(_u.x >> 16)), _m, a1); \
  a2 = fmaf(bf2f((ushort)_u.y), _m, a2); a3 = fmaf(bf2f((ushort)(_u.y >> 16)), _m, a3); \
} while (0)

#define G1STEP(EV) do { \
  int2 _e = (EV); \
  float _m = __int_as_float(_e.y); \
  const uint2* _p = (const uint2*)(y0 + (long)_e.x * 192) + fi; \
  uint2 _u0 = _p[0], _u1 = _p[16], _u2 = _p[32]; \
  a00 = fmaf(bf2f((ushort)_u0.x), _m, a00); a01 = fmaf(bf2f((ushort)(_u0.x >> 16)), _m, a01); \
  a02 = fmaf(bf2f((ushort)_u0.y), _m, a02); a03 = fmaf(bf2f((ushort)(_u0.y >> 16)), _m, a03); \
  a10 = fmaf(bf2f((ushort)_u1.x), _m, a10); a11 = fmaf(bf2f((ushort)(_u1.x >> 16)), _m, a11); \
  a12 = fmaf(bf2f((ushort)_u1.y), _m, a12); a13 = fmaf(bf2f((ushort)(_u1.y >> 16)), _m, a13); \
  a20 = fmaf(bf2f((ushort)_u2.x), _m, a20); a21 = fmaf(bf2f((ushort)(_u2.x >> 16)), _m, a21); \
  a22 = fmaf(bf2f((ushort)_u2.y), _m, a22); a23 = fmaf(bf2f((ushort)(_u2.y >> 16)), _m, a23); \
} while (0)

// ---------------- fused t=0: gather x -> LDS (hi/lo), MFMA, y0 = relu(...) ----------------
__global__ __launch_bounds__(256) void k_l0(
    const int* __restrict__ rowstart, const int2* __restrict__ edges,
    const ushort* __restrict__ xhi, const ushort* __restrict__ xlo,
    const uint4* __restrict__ wfAh, const uint4* __restrict__ wfAl,
    const uint4* __restrict__ wfBh, const uint4* __restrict__ wfBl,
    const float* __restrict__ bias, ushort* __restrict__ y0) {
  __shared__ ushort Gh[64 * 72];
  __shared__ ushort Gl[64 * 72];
  const int wv = threadIdx.x >> 6;
  const int l = threadIdx.x & 63;
  const int grp = l >> 4, fi = l & 15;
  const int nb = blockIdx.x * 64;
  // ---- phase 1: gather x (hi plane), f32 sums -> hi/lo LDS ----
  for (int i = 0; i < 16; ++i) {
    int n = nb + wv * 16 + i;
    float a0 = 0.f, a1 = 0.f, a2 = 0.f, a3 = 0.f;
    if (n < NN) {
      int s = rowstart[n], e = rowstart[n + 1];
      int j = s;
      for (; j + 8 <= e; j += 8) { G0STEP(edges[j + grp]); G0STEP(edges[j + 4 + grp]); }
      if (j + 4 <= e) { G0STEP(edges[j + grp]); j += 4; }
      if (j < e) {
        int idx = j + grp;
        int2 ee = edges[idx < e ? idx : (e - 1)];
        if (idx >= e) ee.y = 0;
        G0STEP(ee);
      }
    }
    RED2(a0); RED2(a1); RED2(a2); RED2(a3);
    if (grp == 0) {
      uint2 uh, ul;
      split2(a0, a1, uh.x, ul.x);
      split2(a2, a3, uh.y, ul.y);
      *(uint2*)&Gh[(wv * 16 + i) * 72 + 4 * fi] = uh;
      *(uint2*)&Gl[(wv * 16 + i) * 72 + 4 * fi] = ul;
    }
  }
  __syncthreads();
  // ---- phase 2: MFMA with hi/lo compensation ----
  const int lg = grp, lr = fi;
  const int tb = nb + wv * 16;
  int ra = tb + lr; if (ra >= NN) ra = NN - 1;
  const long xo = (long)ra * 64 + lg * 8;
  short8 xh0 = *(const short8*)(xhi + xo);
  short8 xh1 = *(const short8*)(xhi + xo + 32);
  short8 xl0 = *(const short8*)(xlo + xo);
  short8 xl1 = *(const short8*)(xlo + xo + 32);
  short8 gh0 = *(const short8*)&Gh[(wv * 16 + lr) * 72 + lg * 8];
  short8 gh1 = *(const short8*)&Gh[(wv * 16 + lr) * 72 + lg * 8 + 32];
  short8 gl0 = *(const short8*)&Gl[(wv * 16 + lr) * 72 + lg * 8];
  short8 gl1 = *(const short8*)&Gl[(wv * 16 + lr) * 72 + lg * 8 + 32];
#pragma unroll
  for (int k = 0; k < 3; ++k) {
    const int k8 = k * 8;
#pragma unroll
    for (int ct = 0; ct < 4; ++ct) {
      short8 ah0 = *(const short8*)&wfAh[(k8 + ct * 2 + 0) * 64 + l];
      short8 ah1 = *(const short8*)&wfAh[(k8 + ct * 2 + 1) * 64 + l];
      short8 al0 = *(const short8*)&wfAl[(k8 + ct * 2 + 0) * 64 + l];
      short8 al1 = *(const short8*)&wfAl[(k8 + ct * 2 + 1) * 64 + l];
      short8 bh0 = *(const short8*)&wfBh[(k8 + ct * 2 + 0) * 64 + l];
      short8 bh1 = *(const short8*)&wfBh[(k8 + ct * 2 + 1) * 64 + l];
      short8 bl0 = *(const short8*)&wfBl[(k8 + ct * 2 + 0) * 64 + l];
      short8 bl1 = *(const short8*)&wfBl[(k8 + ct * 2 + 1) * 64 + l];
      f32x4 acc = {0.f, 0.f, 0.f, 0.f};
      acc = MFMA(gh0, ah0, acc, 0, 0, 0); acc = MFMA(gh1, ah1, acc, 0, 0, 0);
      acc = MFMA(gl0, ah0, acc, 0, 0, 0); acc = MFMA(gl1, ah1, acc, 0, 0, 0);
      acc = MFMA(gh0, al0, acc, 0, 0, 0); acc = MFMA(gh1, al1, acc, 0, 0, 0);
      acc = MFMA(xh0, bh0, acc, 0, 0, 0); acc = MFMA(xh1, bh1, acc, 0, 0, 0);
      acc = MFMA(xl0, bh0, acc, 0, 0, 0); acc = MFMA(xl1, bh1, acc, 0, 0, 0);
      acc = MFMA(xh0, bl0, acc, 0, 0, 0); acc = MFMA(xh1, bl1, acc, 0, 0, 0);
      const int f = ct * 16 + lr;
      const float bv = bias[(k * 2 + 0) * 64 + f];
      ushort* op = y0 + (long)(tb + lg * 4) * 192 + k * 64 + f;
#pragma unroll
      for (int r = 0; r < 4; ++r)
        if (tb + lg * 4 + r < NN) op[(long)r * 192] = f2bf(fmaxf(acc[r] + bv, 0.f));
    }
  }
}

// ---------------- t=1 gather: G(hi/lo)[n][k*64+f] = sum norm * y0[r][k] ----------------
__global__ __launch_bounds__(256) void k_gath1(const int* __restrict__ rowstart,
                                               const int2* __restrict__ edges,
                                               const ushort* __restrict__ y0,
                                               ushort* __restrict__ Ghi,
                                               ushort* __restrict__ Glo) {
  int wave = threadIdx.x >> 6;
  int lane = threadIdx.x & 63;
  int grp = lane >> 4;
  int fi = lane & 15;
  int n = blockIdx.x * 4 + wave;
  if (n >= NN) return;
  int s = rowstart[n], e = rowstart[n + 1];
  float a00 = 0.f, a01 = 0.f, a02 = 0.f, a03 = 0.f;
  float a10 = 0.f, a11 = 0.f, a12 = 0.f, a13 = 0.f;
  float a20 = 0.f, a21 = 0.f, a22 = 0.f, a23 = 0.f;
  int j = s;
  for (; j + 8 <= e; j += 8) { G1STEP(edges[j + grp]); G1STEP(edges[j + 4 + grp]); }
  if (j + 4 <= e) { G1STEP(edges[j + grp]); j += 4; }
  if (j < e) {
    int idx = j + grp;
    int2 ee = edges[idx < e ? idx : (e - 1)];
    if (idx >= e) ee.y = 0;
    G1STEP(ee);
  }
  RED2(a00); RED2(a01); RED2(a02); RED2(a03);
  RED2(a10); RED2(a11); RED2(a12); RED2(a13);
  RED2(a20); RED2(a21); RED2(a22); RED2(a23);
  if (grp < 3) {
    float aX, aY, aZ, aW;
    if (grp == 0)      { aX = a00; aY = a01; aZ = a02; aW = a03; }
    else if (grp == 1) { aX = a10; aY = a11; aZ = a12; aW = a13; }
    else               { aX = a20; aY = a21; aZ = a22; aW = a23; }
    uint2 uh, ul;
    split2(aX, aY, uh.x, ul.x);
    split2(aZ, aW, uh.y, ul.y);
    long o = (long)n * 192 + grp * 64 + 4 * fi;
    *(uint2*)(Ghi + o) = uh;
    *(uint2*)(Glo + o) = ul;
  }
}

// ---------------- t=1 MFMA + mean + BN partials ----------------
__global__ __launch_bounds__(256) void k_gemmY1(
    const ushort* __restrict__ Ghi, const ushort* __restrict__ Glo,
    const ushort* __restrict__ xhi, const ushort* __restrict__ xlo,
    const uint4* __restrict__ wfWh, const uint4* __restrict__ wfWl,
    const uint4* __restrict__ wfRh, const uint4* __restrict__ wfRl,
    const float* __restrict__ bias, float* __restrict__ hm,
    float* __restrict__ bns) {
  __shared__ float bnl[128];
  if (threadIdx.x < 128) bnl[threadIdx.x] = 0.f;
  __syncthreads();
  const int wv = threadIdx.x >> 6;
  const int l = threadIdx.x & 63;
  const int lg = l >> 4, lr = l & 15;
  const int bb = blockIdx.x * 256;
  for (int rt = 0; rt < 4; ++rt) {
    const int tb = bb + rt * 64 + wv * 16;
    int ra = tb + lr; if (ra >= NN) ra = NN - 1;
    const long xo = (long)ra * 64 + lg * 8;
    short8 xh0 = *(const short8*)(xhi + xo);
    short8 xh1 = *(const short8*)(xhi + xo + 32);
    short8 xl0 = *(const short8*)(xlo + xo);
    short8 xl1 = *(const short8*)(xlo + xo + 32);
    f32x4 m0 = {0.f, 0.f, 0.f, 0.f}, m1 = m0, m2 = m0, m3 = m0;
#pragma unroll
    for (int k = 0; k < 3; ++k) {
      const long go = (long)ra * 192 + k * 64 + lg * 8;
      short8 gh0 = *(const short8*)(Ghi + go);
      short8 gh1 = *(const short8*)(Ghi + go + 32);
      short8 gl0 = *(const short8*)(Glo + go);
      short8 gl1 = *(const short8*)(Glo + go + 32);
      const int k8 = k * 8;
#define YCT(CT, M) { \
      short8 wh0 = *(const short8*)&wfWh[(k8 + CT * 2 + 0) * 64 + l]; \
      short8 wh1 = *(const short8*)&wfWh[(k8 + CT * 2 + 1) * 64 + l]; \
      short8 wl0 = *(const short8*)&wfWl[(k8 + CT * 2 + 0) * 64 + l]; \
      short8 wl1 = *(const short8*)&wfWl[(k8 + CT * 2 + 1) * 64 + l]; \
      short8 rh0 = *(const short8*)&wfRh[(k8 + CT * 2 + 0) * 64 + l]; \
      short8 rh1 = *(const short8*)&wfRh[(k8 + CT * 2 + 1) * 64 + l]; \
      short8 rl0 = *(const short8*)&wfRl[(k8 + CT * 2 + 0) * 64 + l]; \
      short8 rl1 = *(const short8*)&wfRl[(k8 + CT * 2 + 1) * 64 + l]; \
      f32x4 acc = {0.f, 0.f, 0.f, 0.f}; \
      acc = MFMA(gh0, wh0, acc, 0, 0, 0); acc = MFMA(gh1, wh1, acc, 0, 0, 0); \
      acc = MFMA(gl0, wh0, acc, 0, 0, 0); acc = MFMA(gl1, wh1, acc, 0, 0, 0); \
      acc = MFMA(gh0, wl0, acc, 0, 0, 0); acc = MFMA(gh1, wl1, acc, 0, 0, 0); \
      acc = MFMA(xh0, rh0, acc, 0, 0, 0); acc = MFMA(xh1, rh1, acc, 0, 0, 0); \
      acc = MFMA(xl0, rh0, acc, 0, 0, 0); acc = MFMA(xl1, rh1, acc, 0, 0, 0); \
      acc = MFMA(xh0, rl0, acc, 0, 0, 0); acc = MFMA(xh1, rl1, acc, 0, 0, 0); \
      float bv = bias[(k * 2 + 1) * 64 + CT * 16 + lr]; \
      M[0] += fmaxf(acc[0] + bv, 0.f); M[1] += fmaxf(acc[1] + bv, 0.f); \
      M[2] += fmaxf(acc[2] + bv, 0.f); M[3] += fmaxf(acc[3] + bv, 0.f); }
      YCT(0, m0) YCT(1, m1) YCT(2, m2) YCT(3, m3)
#undef YCT
    }
    const int rb = tb + lg * 4;
    m0 *= (1.f / 3.f); m1 *= (1.f / 3.f); m2 *= (1.f / 3.f); m3 *= (1.f / 3.f);
#pragma unroll
    for (int r = 0; r < 4; ++r) {
      if (rb + r < NN) {
        float* hp = hm + (long)(rb + r) * 64 + lr;
        hp[0] = m0[r]; hp[16] = m1[r]; hp[32] = m2[r]; hp[48] = m3[r];
      }
    }
#define BNCT(M, CT) { \
    float s = 0.f, q = 0.f; \
    for (int r = 0; r < 4; ++r) if (rb + r < NN) { s += M[r]; q += M[r] * M[r]; } \
    s += __shfl_xor(s, 16); s += __shfl_xor(s, 32); \
    q += __shfl_xor(q, 16); q += __shfl_xor(q, 32); \
    if (lg == 0) { atomicAdd(&bnl[CT * 16 + lr], s); atomicAdd(&bnl[64 + CT * 16 + lr], q); } }
    BNCT(m0, 0) BNCT(m1, 1) BNCT(m2, 2) BNCT(m3, 3)
#undef BNCT
  }
  __syncthreads();
  if (threadIdx.x < 128) atomicAdd(&bns[threadIdx.x], bnl[threadIdx.x]);
}

// ---------------- BN finalize: FINAL -> f32 d_out, else bf16 hi/lo next-layer input ----
template <bool FINAL>
__global__ void k_bnfin(const float* __restrict__ h, const float* __restrict__ sum,
                        const float* __restrict__ sq, const float* __restrict__ gam,
                        const float* __restrict__ bet,
                        float* __restrict__ outf,
                        ushort* __restrict__ ohi, ushort* __restrict__ olo) {
  long i4 = (long)blockIdx.x * 256 + threadIdx.x;
  if (i4 >= (long)NF / 4) return;
  long i = i4 * 4;
  int f = (int)(i & 63);
  float4 v = *(const float4*)(h + i);
  float o[4] = {v.x, v.y, v.z, v.w};
  float r[4];
#pragma unroll
  for (int j = 0; j < 4; ++j) {
    int fj = f + j;
    float mu = sum[fj] * (1.f / NN);
    float var = sq[fj] * (1.f / NN) - mu * mu;
    float inv = rsqrtf(var + EPSBN);
    float y = gam[fj] * (o[j] - mu) * inv + bet[fj];
    r[j] = fmaxf(y, 0.f);
  }
  if (FINAL) {
    float4 ov = {r[0], r[1], r[2], r[3]};
    *(float4*)(outf + i) = ov;
  } else {
    uint2 uh, ul;
    split2(r[0], r[1], uh.x, ul.x);
    split2(r[2], r[3], uh.y, ul.y);
    *(uint2*)(ohi + i) = uh;
    *(uint2*)(olo + i) = ul;
  }
}

extern "C" void kernel_launch(void* const* d_in, const int* in_sizes, int n_in,
                              void* d_out, int out_size, void* d_ws, size_t ws_size,
                              hipStream_t stream) {
  const float* x   = (const float*)d_in[0];
  const int*   ei  = (const int*)d_in[1];
  const float* wts = (const float*)d_in[2];
  const int* row = ei;        // edge_index[0]
  const int* col = ei + NE;   // edge_index[1]

  // workspace layout (4B words; vector arrays 16B-aligned)
  unsigned long long* dc = (unsigned long long*)d_ws;        // 2*NN w
  uint4* wfrag    = (uint4*)((int*)d_ws + 2 * NN);           // 36864 uint4 (147456 w)
  int2*  edges    = (int2*)((int*)wfrag + 147456);           // 2*NE w
  int*   cnt      = (int*)edges + 2 * NE;                    // NN
  int*   rowstart = cnt + NN;                                // NN+4
  int*   cursor   = rowstart + NN + 4;                       // NN
  float* dis      = (float*)(cursor + NN);                   // NN
  float* hm       = dis + NN;                                // NF f32
  ushort* xhi     = (ushort*)(hm + NF);                      // NF bf16
  ushort* xlo     = xhi + NF;                                // NF bf16
  ushort* y0      = xlo + NF;                                // NN*192 bf16 [n][k*64+f]
  ushort* Ghi     = y0 + (long)NN * 192;                     // NN*192 bf16
  ushort* Glo     = Ghi + (long)NN * 192;                    // NN*192 bf16
  float* bns      = (float*)(Glo + (long)NN * 192);          // 128
  int*   part     = (int*)(bns + 128);                       // 512
  int*   pbase    = part + 512;                              // 512

  // --- norm + CSR build + weight frags + x->bf16 hi/lo (once) ---
  hipMemsetAsync(dc, 0, NN * sizeof(unsigned long long), stream);
  int eb = (NE + 255) / 256;
  k_degcnt<<<eb, 256, 0, stream>>>(col, wts, dc);
  k_sblk<<<SBLK, 256, 0, stream>>>(dc, dis, cnt, part);
  k_sscan<<<1, 512, 0, stream>>>(part, pbase);
  k_sfin<<<SBLK, 256, 0, stream>>>(cnt, pbase, rowstart, cursor);
  k_place<<<eb, 256, 0, stream>>>(row, col, wts, dis, cursor, edges);
  for (int L = 0; L < 3; ++L) {
    k_wfrag<<<dim3(12, 8), 64, 0, stream>>>((const float*)d_in[3 + 6 * L],
                                            (const float*)d_in[4 + 6 * L],
                                            (const float*)d_in[5 + 6 * L],
                                            wfrag + (long)L * 12288);
  }
  k_tobf2<<<NF / 4 / 256, 256, 0, stream>>>(x, xhi, xlo);

  int gB = (NN + 3) / 4;            // 25000
  int nfBlocks = NF / 4 / 256;      // 6250

  for (int layer = 0; layer < 3; ++layer) {
    const float* bs = (const float*)d_in[6 + 6 * layer];  // [K,2,1,F]
    const float* gm = (const float*)d_in[7 + 6 * layer];  // [F]
    const float* bt = (const float*)d_in[8 + 6 * layer];  // [F]
    const uint4* wfL = wfrag + (long)layer * 12288;
    // hi tables: iw=+0, w=+1536, rw0=+3072, rw1=+4608; lo = +6144 each

    // t=0 fused: y0[n][k] = relu((A@x)@iw_k + x@rw0_k + b0_k)   [hi/lo compensated]
    k_l0<<<BLK64, 256, 0, stream>>>(rowstart, edges, xhi, xlo,
                                    wfL + 0, wfL + 6144, wfL + 3072, wfL + 3072 + 6144,
                                    bs, y0);
    // t=1: G = A@y0 (hi/lo); hm = mean_k relu(G@w_k + x@rw1_k + b1_k) + BN partials
    hipMemsetAsync(bns, 0, 2 * 64 * sizeof(float), stream);
    k_gath1<<<gB, 256, 0, stream>>>(rowstart, edges, y0, Ghi, Glo);
    k_gemmY1<<<SBLK, 256, 0, stream>>>(Ghi, Glo, xhi, xlo,
                                       wfL + 1536, wfL + 1536 + 6144,
                                       wfL + 4608, wfL + 4608 + 6144,
                                       bs, hm, bns);
    // BN finalize + relu
    if (layer == 2)
      k_bnfin<true><<<nfBlocks, 256, 0, stream>>>(hm, bns, bns + 64, gm, bt,
                                                  (float*)d_out, (ushort*)0, (ushort*)0);
    else
      k_bnfin<false><<<nfBlocks, 256, 0, stream>>>(hm, bns, bns + 64, gm, bt,
                                                   (float*)0, xhi, xlo);
  }
}

// Round 15
// 972.274 us; speedup vs baseline: 1.0003x; 1.0003x over previous
//
#include <hip/hip_runtime.h>

#define NN 100000
#define NE 1600000
#define FD 64
#define KK 3
#define NF (NN*FD)            // 6,400,000
#define EPSBN 1e-5f
#define SBLK ((NN + 255) / 256)   // 391
#define BLK64 ((NN + 63) / 64)    // 1563
#define DEGSCALE 262144.0f        // 2^18 fixed-point for weighted degree

typedef unsigned short ushort;
typedef unsigned int uint;
typedef __attribute__((ext_vector_type(8))) short short8;
typedef __attribute__((ext_vector_type(4))) float f32x4;

#define MFMA __builtin_amdgcn_mfma_f32_16x16x32_bf16

__device__ inline float bf2f(ushort u) { return __uint_as_float((unsigned)u << 16); }
__device__ inline ushort f2bf(float v) {
  unsigned u = __float_as_uint(v); u += 0x7FFF + ((u >> 16) & 1);
  return (ushort)(u >> 16);
}
// split a,b into packed hi-word and lo-word (hi = rnd(v), lo = rnd(v - hi))
__device__ inline void split2(float a, float b, uint& hi, uint& lo) {
  ushort ha = f2bf(a), hb = f2bf(b);
  float ra = a - bf2f(ha), rb = b - bf2f(hb);
  hi = (uint)ha | ((uint)hb << 16);
  lo = (uint)f2bf(ra) | ((uint)f2bf(rb) << 16);
}

// ---------------- graph norm + CSR build ----------------
__global__ void k_degcnt(const int* __restrict__ col, const float* __restrict__ w,
                         unsigned long long* __restrict__ dc) {
  int e = blockIdx.x * 256 + threadIdx.x;
  if (e < NE) {
    unsigned fx = __float2uint_rn(w[e] * DEGSCALE);
    atomicAdd(&dc[col[e]], (1ULL << 32) | (unsigned long long)fx);
  }
}

__global__ __launch_bounds__(256) void k_sblk(const unsigned long long* __restrict__ dc,
                                              float* __restrict__ dis, int* __restrict__ cnt,
                                              int* __restrict__ part) {
  int i = blockIdx.x * 256 + threadIdx.x;
  int v = 0;
  if (i < NN) {
    unsigned long long u = dc[i];
    float d = (float)(unsigned)u * (1.0f / DEGSCALE);
    dis[i] = d > 0.f ? rsqrtf(d) : 0.f;
    v = (int)(u >> 32);
    cnt[i] = v;
  }
#pragma unroll
  for (int off = 32; off; off >>= 1) v += __shfl_down(v, off);
  __shared__ int ws[4];
  if ((threadIdx.x & 63) == 0) ws[threadIdx.x >> 6] = v;
  __syncthreads();
  if (threadIdx.x == 0) part[blockIdx.x] = ws[0] + ws[1] + ws[2] + ws[3];
}

__global__ __launch_bounds__(512) void k_sscan(const int* __restrict__ part,
                                               int* __restrict__ base) {
  __shared__ int ls[512];
  int tid = threadIdx.x;
  int v = (tid < SBLK) ? part[tid] : 0;
  ls[tid] = v;
  __syncthreads();
  for (int off = 1; off < 512; off <<= 1) {
    int u = (tid >= off) ? ls[tid - off] : 0;
    __syncthreads();
    ls[tid] += u;
    __syncthreads();
  }
  base[tid] = tid ? ls[tid - 1] : 0;
}

__global__ __launch_bounds__(256) void k_sfin(const int* __restrict__ cnt,
                                              const int* __restrict__ base,
                                              int* __restrict__ rowstart,
                                              int* __restrict__ cursor) {
  __shared__ int ls[256];
  int i = blockIdx.x * 256 + threadIdx.x;
  int v = (i < NN) ? cnt[i] : 0;
  ls[threadIdx.x] = v;
  __syncthreads();
  for (int off = 1; off < 256; off <<= 1) {
    int u = (threadIdx.x >= off) ? ls[threadIdx.x - off] : 0;
    __syncthreads();
    ls[threadIdx.x] += u;
    __syncthreads();
  }
  int excl = base[blockIdx.x] + ls[threadIdx.x] - v;
  if (i < NN) {
    rowstart[i] = excl;
    cursor[i] = excl;
    if (i == NN - 1) rowstart[NN] = excl + v;
  }
}

__global__ void k_place(const int* __restrict__ row, const int* __restrict__ col,
                        const float* __restrict__ w, const float* __restrict__ dis,
                        int* __restrict__ cursor, int2* __restrict__ edges) {
  int e = blockIdx.x * 256 + threadIdx.x;
  if (e >= NE) return;
  int r = row[e], c = col[e];
  float nm = dis[r] * w[e] * dis[c];
  int p = atomicAdd(&cursor[c], 1);
  edges[p] = make_int2(r, __float_as_int(nm));
}

// ---------------- weight fragment prep (per layer, hi + lo) ----------------
// hi frag[(which*3+k)*8 + ct*2 + ks][lane]; lo at +6144 uint4.
// which: 0 = iw[k], 1 = w[k][0], 2 = rw[k][0], 3 = rw[k][1]
__global__ __launch_bounds__(64) void k_wfrag(const float* __restrict__ iw,
                                              const float* __restrict__ w,
                                              const float* __restrict__ rw,
                                              uint4* __restrict__ frag) {
  int m = blockIdx.x;
  int which = m / 3, k = m % 3;
  const float* src;
  if (which == 0) src = iw + k * 4096;
  else if (which == 1) src = w + k * 4096;
  else if (which == 2) src = rw + k * 8192;
  else src = rw + k * 8192 + 4096;
  int sub = blockIdx.y;            // ct*2 + ks
  int ks = sub & 1, ct = sub >> 1;
  int l = threadIdx.x;
  int r0 = ks * 32 + (l >> 4) * 8;
  int c = ct * 16 + (l & 15);
  uint4 oh, ol;
  split2(src[(r0 + 0) * 64 + c], src[(r0 + 1) * 64 + c], oh.x, ol.x);
  split2(src[(r0 + 2) * 64 + c], src[(r0 + 3) * 64 + c], oh.y, ol.y);
  split2(src[(r0 + 4) * 64 + c], src[(r0 + 5) * 64 + c], oh.z, ol.z);
  split2(src[(r0 + 6) * 64 + c], src[(r0 + 7) * 64 + c], oh.w, ol.w);
  frag[(m * 8 + sub) * 64 + l] = oh;
  frag[6144 + (m * 8 + sub) * 64 + l] = ol;
}

// ---------------- f32 -> bf16 hi/lo planes ----------------
__global__ void k_tobf2(const float* __restrict__ in,
                        ushort* __restrict__ hi, ushort* __restrict__ lo) {
  long i = ((long)blockIdx.x * 256 + threadIdx.x) * 4;
  float4 v = *(const float4*)(in + i);
  uint2 uh, ul;
  split2(v.x, v.y, uh.x, ul.x);
  split2(v.z, v.w, uh.y, ul.y);
  *(uint2*)(hi + i) = uh;
  *(uint2*)(lo + i) = ul;
}

#define RED3(v) do { (v) += __shfl_xor((v), 8); (v) += __shfl_xor((v), 16); (v) += __shfl_xor((v), 32); } while (0)

// 8-edge-slot gather step: lane owns 8 features (uint4 = 8 bf16) of one plane read
#define G0ST8(EV) do { \
  int2 _e = (EV); \
  float _m = __int_as_float(_e.y); \
  uint4 _u = ((const uint4*)(xhi + (long)_e.x * 64))[fi4]; \
  a0 = fmaf(bf2f((ushort)_u.x), _m, a0); a1 = fmaf(bf2f((ushort)(_u.x >> 16)), _m, a1); \
  a2 = fmaf(bf2f((ushort)_u.y), _m, a2); a3 = fmaf(bf2f((ushort)(_u.y >> 16)), _m, a3); \
  a4 = fmaf(bf2f((ushort)_u.z), _m, a4); a5 = fmaf(bf2f((ushort)(_u.z >> 16)), _m, a5); \
  a6 = fmaf(bf2f((ushort)_u.w), _m, a6); a7 = fmaf(bf2f((ushort)(_u.w >> 16)), _m, a7); \
} while (0)

#define G1ST8(EV) do { \
  int2 _e = (EV); \
  float _m = __int_as_float(_e.y); \
  const uint4* _p = (const uint4*)(y0 + (long)_e.x * 192) + fi4; \
  uint4 _u0 = _p[0], _u1 = _p[8], _u2 = _p[16]; \
  a00 = fmaf(bf2f((ushort)_u0.x), _m, a00); a01 = fmaf(bf2f((ushort)(_u0.x >> 16)), _m, a01); \
  a02 = fmaf(bf2f((ushort)_u0.y), _m, a02); a03 = fmaf(bf2f((ushort)(_u0.y >> 16)), _m, a03); \
  a04 = fmaf(bf2f((ushort)_u0.z), _m, a04); a05 = fmaf(bf2f((ushort)(_u0.z >> 16)), _m, a05); \
  a06 = fmaf(bf2f((ushort)_u0.w), _m, a06); a07 = fmaf(bf2f((ushort)(_u0.w >> 16)), _m, a07); \
  a10 = fmaf(bf2f((ushort)_u1.x), _m, a10); a11 = fmaf(bf2f((ushort)(_u1.x >> 16)), _m, a11); \
  a12 = fmaf(bf2f((ushort)_u1.y), _m, a12); a13 = fmaf(bf2f((ushort)(_u1.y >> 16)), _m, a13); \
  a14 = fmaf(bf2f((ushort)_u1.z), _m, a14); a15 = fmaf(bf2f((ushort)(_u1.z >> 16)), _m, a15); \
  a16 = fmaf(bf2f((ushort)_u1.w), _m, a16); a17 = fmaf(bf2f((ushort)(_u1.w >> 16)), _m, a17); \
  a20 = fmaf(bf2f((ushort)_u2.x), _m, a20); a21 = fmaf(bf2f((ushort)(_u2.x >> 16)), _m, a21); \
  a22 = fmaf(bf2f((ushort)_u2.y), _m, a22); a23 = fmaf(bf2f((ushort)(_u2.y >> 16)), _m, a23); \
  a24 = fmaf(bf2f((ushort)_u2.z), _m, a24); a25 = fmaf(bf2f((ushort)(_u2.z >> 16)), _m, a25); \
  a26 = fmaf(bf2f((ushort)_u2.w), _m, a26); a27 = fmaf(bf2f((ushort)(_u2.w >> 16)), _m, a27); \
} while (0)

// ---------------- fused t=0: gather x -> LDS (hi/lo), MFMA, y0 = relu(...) ----------------
__global__ __launch_bounds__(256) void k_l0(
    const int* __restrict__ rowstart, const int2* __restrict__ edges,
    const ushort* __restrict__ xhi, const ushort* __restrict__ xlo,
    const uint4* __restrict__ wfAh, const uint4* __restrict__ wfAl,
    const uint4* __restrict__ wfBh, const uint4* __restrict__ wfBl,
    const float* __restrict__ bias, ushort* __restrict__ y0) {
  __shared__ ushort Gh[64 * 72];
  __shared__ ushort Gl[64 * 72];
  const int wv = threadIdx.x >> 6;
  const int l = threadIdx.x & 63;
  const int g8 = l >> 3, fi4 = l & 7;   // phase 1: edge slot / feature quad
  const int nb = blockIdx.x * 64;
  // ---- phase 1: gather x (hi plane), f32 sums -> hi/lo LDS ----
  for (int i = 0; i < 16; ++i) {
    int n = nb + wv * 16 + i;
    float a0 = 0.f, a1 = 0.f, a2 = 0.f, a3 = 0.f;
    float a4 = 0.f, a5 = 0.f, a6 = 0.f, a7 = 0.f;
    if (n < NN) {
      int s = rowstart[n], e = rowstart[n + 1];
      int j = s;
      for (; j + 8 <= e; j += 8) G0ST8(edges[j + g8]);
      if (j < e) {
        int idx = j + g8;
        int2 ee = edges[idx < e ? idx : (e - 1)];
        if (idx >= e) ee.y = 0;
        G0ST8(ee);
      }
    }
    RED3(a0); RED3(a1); RED3(a2); RED3(a3);
    RED3(a4); RED3(a5); RED3(a6); RED3(a7);
    if (g8 == 0) {
      uint4 uh, ul;
      split2(a0, a1, uh.x, ul.x);
      split2(a2, a3, uh.y, ul.y);
      split2(a4, a5, uh.z, ul.z);
      split2(a6, a7, uh.w, ul.w);
      *(uint4*)&Gh[(wv * 16 + i) * 72 + 8 * fi4] = uh;
      *(uint4*)&Gl[(wv * 16 + i) * 72 + 8 * fi4] = ul;
    }
  }
  __syncthreads();
  // ---- phase 2: MFMA with hi/lo compensation ----
  const int lg = l >> 4, lr = l & 15;
  const int tb = nb + wv * 16;
  int ra = tb + lr; if (ra >= NN) ra = NN - 1;
  const long xo = (long)ra * 64 + lg * 8;
  short8 xh0 = *(const short8*)(xhi + xo);
  short8 xh1 = *(const short8*)(xhi + xo + 32);
  short8 xl0 = *(const short8*)(xlo + xo);
  short8 xl1 = *(const short8*)(xlo + xo + 32);
  short8 gh0 = *(const short8*)&Gh[(wv * 16 + lr) * 72 + lg * 8];
  short8 gh1 = *(const short8*)&Gh[(wv * 16 + lr) * 72 + lg * 8 + 32];
  short8 gl0 = *(const short8*)&Gl[(wv * 16 + lr) * 72 + lg * 8];
  short8 gl1 = *(const short8*)&Gl[(wv * 16 + lr) * 72 + lg * 8 + 32];
#pragma unroll
  for (int k = 0; k < 3; ++k) {
    const int k8 = k * 8;
#pragma unroll
    for (int ct = 0; ct < 4; ++ct) {
      short8 ah0 = *(const short8*)&wfAh[(k8 + ct * 2 + 0) * 64 + l];
      short8 ah1 = *(const short8*)&wfAh[(k8 + ct * 2 + 1) * 64 + l];
      short8 al0 = *(const short8*)&wfAl[(k8 + ct * 2 + 0) * 64 + l];
      short8 al1 = *(const short8*)&wfAl[(k8 + ct * 2 + 1) * 64 + l];
      short8 bh0 = *(const short8*)&wfBh[(k8 + ct * 2 + 0) * 64 + l];
      short8 bh1 = *(const short8*)&wfBh[(k8 + ct * 2 + 1) * 64 + l];
      short8 bl0 = *(const short8*)&wfBl[(k8 + ct * 2 + 0) * 64 + l];
      short8 bl1 = *(const short8*)&wfBl[(k8 + ct * 2 + 1) * 64 + l];
      f32x4 acc = {0.f, 0.f, 0.f, 0.f};
      acc = MFMA(gh0, ah0, acc, 0, 0, 0); acc = MFMA(gh1, ah1, acc, 0, 0, 0);
      acc = MFMA(gl0, ah0, acc, 0, 0, 0); acc = MFMA(gl1, ah1, acc, 0, 0, 0);
      acc = MFMA(gh0, al0, acc, 0, 0, 0); acc = MFMA(gh1, al1, acc, 0, 0, 0);
      acc = MFMA(xh0, bh0, acc, 0, 0, 0); acc = MFMA(xh1, bh1, acc, 0, 0, 0);
      acc = MFMA(xl0, bh0, acc, 0, 0, 0); acc = MFMA(xl1, bh1, acc, 0, 0, 0);
      acc = MFMA(xh0, bl0, acc, 0, 0, 0); acc = MFMA(xh1, bl1, acc, 0, 0, 0);
      const int f = ct * 16 + lr;
      const float bv = bias[(k * 2 + 0) * 64 + f];
      ushort* op = y0 + (long)(tb + lg * 4) * 192 + k * 64 + f;
#pragma unroll
      for (int r = 0; r < 4; ++r)
        if (tb + lg * 4 + r < NN) op[(long)r * 192] = f2bf(fmaxf(acc[r] + bv, 0.f));
    }
  }
}

// ---------------- t=1 gather: G(hi/lo)[n][k*64+f] = sum norm * y0[r][k] ----------------
__global__ __launch_bounds__(256) void k_gath1(const int* __restrict__ rowstart,
                                               const int2* __restrict__ edges,
                                               const ushort* __restrict__ y0,
                                               ushort* __restrict__ Ghi,
                                               ushort* __restrict__ Glo) {
  int wave = threadIdx.x >> 6;
  int lane = threadIdx.x & 63;
  int g8 = lane >> 3;        // edge slot 0..7
  int fi4 = lane & 7;        // features 8*fi4 .. +7
  int n = blockIdx.x * 4 + wave;
  if (n >= NN) return;
  int s = rowstart[n], e = rowstart[n + 1];
  float a00 = 0.f, a01 = 0.f, a02 = 0.f, a03 = 0.f, a04 = 0.f, a05 = 0.f, a06 = 0.f, a07 = 0.f;
  float a10 = 0.f, a11 = 0.f, a12 = 0.f, a13 = 0.f, a14 = 0.f, a15 = 0.f, a16 = 0.f, a17 = 0.f;
  float a20 = 0.f, a21 = 0.f, a22 = 0.f, a23 = 0.f, a24 = 0.f, a25 = 0.f, a26 = 0.f, a27 = 0.f;
  int j = s;
  for (; j + 8 <= e; j += 8) G1ST8(edges[j + g8]);
  if (j < e) {
    int idx = j + g8;
    int2 ee = edges[idx < e ? idx : (e - 1)];
    if (idx >= e) ee.y = 0;
    G1ST8(ee);
  }
  RED3(a00); RED3(a01); RED3(a02); RED3(a03); RED3(a04); RED3(a05); RED3(a06); RED3(a07);
  RED3(a10); RED3(a11); RED3(a12); RED3(a13); RED3(a14); RED3(a15); RED3(a16); RED3(a17);
  RED3(a20); RED3(a21); RED3(a22); RED3(a23); RED3(a24); RED3(a25); RED3(a26); RED3(a27);
  if (g8 < 3) {
    uint4 uh, ul;
    if (g8 == 0) {
      split2(a00, a01, uh.x, ul.x); split2(a02, a03, uh.y, ul.y);
      split2(a04, a05, uh.z, ul.z); split2(a06, a07, uh.w, ul.w);
    } else if (g8 == 1) {
      split2(a10, a11, uh.x, ul.x); split2(a12, a13, uh.y, ul.y);
      split2(a14, a15, uh.z, ul.z); split2(a16, a17, uh.w, ul.w);
    } else {
      split2(a20, a21, uh.x, ul.x); split2(a22, a23, uh.y, ul.y);
      split2(a24, a25, uh.z, ul.z); split2(a26, a27, uh.w, ul.w);
    }
    long o = (long)n * 192 + g8 * 64 + 8 * fi4;
    *(uint4*)(Ghi + o) = uh;
    *(uint4*)(Glo + o) = ul;
  }
}

// ---------------- t=1 MFMA + mean + BN partials ----------------
__global__ __launch_bounds__(256) void k_gemmY1(
    const ushort* __restrict__ Ghi, const ushort* __restrict__ Glo,
    const ushort* __restrict__ xhi, const ushort* __restrict__ xlo,
    const uint4* __restrict__ wfWh, const uint4* __restrict__ wfWl,
    const uint4* __restrict__ wfRh, const uint4* __restrict__ wfRl,
    const float* __restrict__ bias, float* __restrict__ hm,
    float* __restrict__ bns) {
  __shared__ float bnl[128];
  if (threadIdx.x < 128) bnl[threadIdx.x] = 0.f;
  __syncthreads();
  const int wv = threadIdx.x >> 6;
  const int l = threadIdx.x & 63;
  const int lg = l >> 4, lr = l & 15;
  const int bb = blockIdx.x * 256;
  for (int rt = 0; rt < 4; ++rt) {
    const int tb = bb + rt * 64 + wv * 16;
    int ra = tb + lr; if (ra >= NN) ra = NN - 1;
    const long xo = (long)ra * 64 + lg * 8;
    short8 xh0 = *(const short8*)(xhi + xo);
    short8 xh1 = *(const short8*)(xhi + xo + 32);
    short8 xl0 = *(const short8*)(xlo + xo);
    short8 xl1 = *(const short8*)(xlo + xo + 32);
    f32x4 m0 = {0.f, 0.f, 0.f, 0.f}, m1 = m0, m2 = m0, m3 = m0;
#pragma unroll
    for (int k = 0; k < 3; ++k) {
      const long go = (long)ra * 192 + k * 64 + lg * 8;
      short8 gh0 = *(const short8*)(Ghi + go);
      short8 gh1 = *(const short8*)(Ghi + go + 32);
      short8 gl0 = *(const short8*)(Glo + go);
      short8 gl1 = *(const short8*)(Glo + go + 32);
      const int k8 = k * 8;
#define YCT(CT, M) { \
      short8 wh0 = *(const short8*)&wfWh[(k8 + CT * 2 + 0) * 64 + l]; \
      short8 wh1 = *(const short8*)&wfWh[(k8 + CT * 2 + 1) * 64 + l]; \
      short8 wl0 = *(const short8*)&wfWl[(k8 + CT * 2 + 0) * 64 + l]; \
      short8 wl1 = *(const short8*)&wfWl[(k8 + CT * 2 + 1) * 64 + l]; \
      short8 rh0 = *(const short8*)&wfRh[(k8 + CT * 2 + 0) * 64 + l]; \
      short8 rh1 = *(const short8*)&wfRh[(k8 + CT * 2 + 1) * 64 + l]; \
      short8 rl0 = *(const short8*)&wfRl[(k8 + CT * 2 + 0) * 64 + l]; \
      short8 rl1 = *(const short8*)&wfRl[(k8 + CT * 2 + 1) * 64 + l]; \
      f32x4 acc = {0.f, 0.f, 0.f, 0.f}; \
      acc = MFMA(gh0, wh0, acc, 0, 0, 0); acc = MFMA(gh1, wh1, acc, 0, 0, 0); \
      acc = MFMA(gl0, wh0, acc, 0, 0, 0); acc = MFMA(gl1, wh1, acc, 0, 0, 0); \
      acc = MFMA(gh0, wl0, acc, 0, 0, 0); acc = MFMA(gh1, wl1, acc, 0, 0, 0); \
      acc = MFMA(xh0, rh0, acc, 0, 0, 0); acc = MFMA(xh1, rh1, acc, 0, 0, 0); \
      acc = MFMA(xl0, rh0, acc, 0, 0, 0); acc = MFMA(xl1, rh1, acc, 0, 0, 0); \
      acc = MFMA(xh0, rl0, acc, 0, 0, 0); acc = MFMA(xh1, rl1, acc, 0, 0, 0); \
      float bv = bias[(k * 2 + 1) * 64 + CT * 16 + lr]; \
      M[0] += fmaxf(acc[0] + bv, 0.f); M[1] += fmaxf(acc[1] + bv, 0.f); \
      M[2] += fmaxf(acc[2] + bv, 0.f); M[3] += fmaxf(acc[3] + bv, 0.f); }
      YCT(0, m0) YCT(1, m1) YCT(2, m2) YCT(3, m3)
#undef YCT
    }
    const int rb = tb + lg * 4;
    m0 *= (1.f / 3.f); m1 *= (1.f / 3.f); m2 *= (1.f / 3.f); m3 *= (1.f / 3.f);
#pragma unroll
    for (int r = 0; r < 4; ++r) {
      if (rb + r < NN) {
        float* hp = hm + (long)(rb + r) * 64 + lr;
        hp[0] = m0[r]; hp[16] = m1[r]; hp[32] = m2[r]; hp[48] = m3[r];
      }
    }
#define BNCT(M, CT) { \
    float s = 0.f, q = 0.f; \
    for (int r = 0; r < 4; ++r) if (rb + r < NN) { s += M[r]; q += M[r] * M[r]; } \
    s += __shfl_xor(s, 16); s += __shfl_xor(s, 32); \
    q += __shfl_xor(q, 16); q += __shfl_xor(q, 32); \
    if (lg == 0) { atomicAdd(&bnl[CT * 16 + lr], s); atomicAdd(&bnl[64 + CT * 16 + lr], q); } }
    BNCT(m0, 0) BNCT(m1, 1) BNCT(m2, 2) BNCT(m3, 3)
#undef BNCT
  }
  __syncthreads();
  if (threadIdx.x < 128) atomicAdd(&bns[threadIdx.x], bnl[threadIdx.x]);
}

// ---------------- BN finalize: FINAL -> f32 d_out, else bf16 hi/lo next-layer input ----
template <bool FINAL>
__global__ void k_bnfin(const float* __restrict__ h, const float* __restrict__ sum,
                        const float* __restrict__ sq, const float* __restrict__ gam,
                        const float* __restrict__ bet,
                        float* __restrict__ outf,
                        ushort* __restrict__ ohi, ushort* __restrict__ olo) {
  long i4 = (long)blockIdx.x * 256 + threadIdx.x;
  if (i4 >= (long)NF / 4) return;
  long i = i4 * 4;
  int f = (int)(i & 63);
  float4 v = *(const float4*)(h + i);
  float o[4] = {v.x, v.y, v.z, v.w};
  float r[4];
#pragma unroll
  for (int j = 0; j < 4; ++j) {
    int fj = f + j;
    float mu = sum[fj] * (1.f / NN);
    float var = sq[fj] * (1.f / NN) - mu * mu;
    float inv = rsqrtf(var + EPSBN);
    float y = gam[fj] * (o[j] - mu) * inv + bet[fj];
    r[j] = fmaxf(y, 0.f);
  }
  if (FINAL) {
    float4 ov = {r[0], r[1], r[2], r[3]};
    *(float4*)(outf + i) = ov;
  } else {
    uint2 uh, ul;
    split2(r[0], r[1], uh.x, ul.x);
    split2(r[2], r[3], uh.y, ul.y);
    *(uint2*)(ohi + i) = uh;
    *(uint2*)(olo + i) = ul;
  }
}

extern "C" void kernel_launch(void* const* d_in, const int* in_sizes, int n_in,
                              void* d_out, int out_size, void* d_ws, size_t ws_size,
                              hipStream_t stream) {
  const float* x   = (const float*)d_in[0];
  const int*   ei  = (const int*)d_in[1];
  const float* wts = (const float*)d_in[2];
  const int* row = ei;        // edge_index[0]
  const int* col = ei + NE;   // edge_index[1]

  // workspace layout (4B words; vector arrays 16B-aligned)
  unsigned long long* dc = (unsigned long long*)d_ws;        // 2*NN w
  uint4* wfrag    = (uint4*)((int*)d_ws + 2 * NN);           // 36864 uint4 (147456 w)
  int2*  edges    = (int2*)((int*)wfrag + 147456);           // 2*NE w
  int*   cnt      = (int*)edges + 2 * NE;                    // NN
  int*   rowstart = cnt + NN;                                // NN+4
  int*   cursor   = rowstart + NN + 4;                       // NN
  float* dis      = (float*)(cursor + NN);                   // NN
  float* hm       = dis + NN;                                // NF f32
  ushort* xhi     = (ushort*)(hm + NF);                      // NF bf16
  ushort* xlo     = xhi + NF;                                // NF bf16
  ushort* y0      = xlo + NF;                                // NN*192 bf16 [n][k*64+f]
  ushort* Ghi     = y0 + (long)NN * 192;                     // NN*192 bf16
  ushort* Glo     = Ghi + (long)NN * 192;                    // NN*192 bf16
  float* bns      = (float*)(Glo + (long)NN * 192);          // 128
  int*   part     = (int*)(bns + 128);                       // 512
  int*   pbase    = part + 512;                              // 512

  // --- norm + CSR build + weight frags + x->bf16 hi/lo (once) ---
  hipMemsetAsync(dc, 0, NN * sizeof(unsigned long long), stream);
  int eb = (NE + 255) / 256;
  k_degcnt<<<eb, 256, 0, stream>>>(col, wts, dc);
  k_sblk<<<SBLK, 256, 0, stream>>>(dc, dis, cnt, part);
  k_sscan<<<1, 512, 0, stream>>>(part, pbase);
  k_sfin<<<SBLK, 256, 0, stream>>>(cnt, pbase, rowstart, cursor);
  k_place<<<eb, 256, 0, stream>>>(row, col, wts, dis, cursor, edges);
  for (int L = 0; L < 3; ++L) {
    k_wfrag<<<dim3(12, 8), 64, 0, stream>>>((const float*)d_in[3 + 6 * L],
                                            (const float*)d_in[4 + 6 * L],
                                            (const float*)d_in[5 + 6 * L],
                                            wfrag + (long)L * 12288);
  }
  k_tobf2<<<NF / 4 / 256, 256, 0, stream>>>(x, xhi, xlo);

  int gB = (NN + 3) / 4;            // 25000
  int nfBlocks = NF / 4 / 256;      // 6250

  for (int layer = 0; layer < 3; ++layer) {
    const float* bs = (const float*)d_in[6 + 6 * layer];  // [K,2,1,F]
    const float* gm = (const float*)d_in[7 + 6 * layer];  // [F]
    const float* bt = (const float*)d_in[8 + 6 * layer];  // [F]
    const uint4* wfL = wfrag + (long)layer * 12288;
    // hi tables: iw=+0, w=+1536, rw0=+3072, rw1=+4608; lo = +6144 each

    // t=0 fused: y0[n][k] = relu((A@x)@iw_k + x@rw0_k + b0_k)   [hi/lo compensated]
    k_l0<<<BLK64, 256, 0, stream>>>(rowstart, edges, xhi, xlo,
                                    wfL + 0, wfL + 6144, wfL + 3072, wfL + 3072 + 6144,
                                    bs, y0);
    // t=1: G = A@y0 (hi/lo); hm = mean_k relu(G@w_k + x@rw1_k + b1_k) + BN partials
    hipMemsetAsync(bns, 0, 2 * 64 * sizeof(float), stream);
    k_gath1<<<gB, 256, 0, stream>>>(rowstart, edges, y0, Ghi, Glo);
    k_gemmY1<<<SBLK, 256, 0, stream>>>(Ghi, Glo, xhi, xlo,
                                       wfL + 1536, wfL + 1536 + 6144,
                                       wfL + 4608, wfL + 4608 + 6144,
                                       bs, hm, bns);
    // BN finalize + relu
    if (layer == 2)
      k_bnfin<true><<<nfBlocks, 256, 0, stream>>>(hm, bns, bns + 64, gm, bt,
                                                  (float*)d_out, (ushort*)0, (ushort*)0);
    else
      k_bnfin<false><<<nfBlocks, 256, 0, stream>>>(hm, bns, bns + 64, gm, bt,
                                                   (float*)0, xhi, xlo);
  }
}